// Round 13
// baseline (303.737 us; speedup 1.0000x reference)
//
#include <hip/hip_runtime.h>

typedef unsigned short ushort_t;
typedef __attribute__((ext_vector_type(8))) short bf16x8;    // 8 bf16 = 4 VGPRs
typedef __attribute__((ext_vector_type(16))) float f32x16;   // 32x32 MFMA acc

#define MAXN 8192
#define CAND_CAP 2048
#define CAND_SEG 512
#define CHUNK_CAP 8192   // round-15: single GEMM2 dispatch beats 2 half-size ones

// round-21 journal:
//   r18: 234.0 best (GEMM2 96.5, FETCH 181MB, conflicts 8.5M = b128 floor).
//   r19 (unroll m16): 233.1 NULL -> topk not scratch-bound.
//   r20 (wave topk, 2 sweeps): 246.8 REGRESSION +14 -> the re-read sweep
//   costs ~14us (L3 re-fetch of the 128MB score buffer); values MUST stay
//   reg-resident. Barriers were worth less than the traffic added.
//   r21: topk_fast = legacy layout (single sweep, 32 vals/thread in regs)
//   minus the serialization: PER-WAVE thresholds (proof: v in top-k and
//   v < L_w => >=k lane-maxima in wave w exceed v => contradiction; valid
//   for k<=64), ballot bisection (no histograms), ballot-prefix compaction
//   into per-wave LDS segments (no atomics), ONE barrier (was 7), merged
//   rank-by-count. Expected ~93 cand/wave << 512 cap.

// ---- zero-prefill d_out (safety) ----
__global__ void prefill_kernel(float* __restrict__ out, int n) {
    for (int i = blockIdx.x * 256 + threadIdx.x; i < n; i += gridDim.x * 256)
        out[i] = 0.0f;
}

// ---- f32 -> bf16 cast (RNE), 8/thread ----
__global__ __launch_bounds__(256) void cast_bf16_kernel(
    const float* __restrict__ in, ushort_t* __restrict__ out, int n)
{
    int i = (blockIdx.x * 256 + threadIdx.x) * 8;
    if (i >= n) return;
    ushort_t o[8];
#pragma unroll
    for (int q = 0; q < 8; ++q) {
        unsigned u = __float_as_uint(in[i + q]);
        o[q] = (ushort_t)((u + 0x7FFFu + ((u >> 16) & 1u)) >> 16);
    }
    *(ushort4*)(out + i)     = make_ushort4(o[0], o[1], o[2], o[3]);
    *(ushort4*)(out + i + 4) = make_ushort4(o[4], o[5], o[6], o[7]);
}

// async global->LDS, 16B per lane; lds dest = wave-uniform base + lane*16
__device__ __forceinline__ void gload_lds16(const ushort_t* g, void* lds) {
    __builtin_amdgcn_global_load_lds(
        (const __attribute__((address_space(1))) unsigned int*)g,
        (__attribute__((address_space(3))) unsigned int*)lds, 16, 0, 0);
}

// ---- bf16 MFMA NT GEMM: C[i][j] = bf16(sum_k A[i][k]*B[j][k] (+bias[j])) ----
// 128x128 block tile, BK=64, 4 waves 2x2; wave tile 64x64 = 2x2 of 32x32x16.
// __launch_bounds__(256,4) -> 4 blocks/CU.
// tri=1: PACKED triangular grid — blockIdx.x flat over live tiles only,
// with bijective XCD-chunk swizzle (m204) — r18: FETCH 224->181MB, keep.
// LDS 16B-slot swizzle: slot(m,kq) = m*8 + (kq ^ (m&7))  [conflict floor:
// residual 8.5M SQ_LDS_BANK_CONFLICT = inherent 2-way b128 aliasing, free].
__global__ __launch_bounds__(256, 4) void gemm_bf16_nt(
    const ushort_t* __restrict__ A, const ushort_t* __restrict__ B,
    const float* __restrict__ bias, ushort_t* __restrict__ C,
    int K, int ldc, int tbase, int tri)
{
    int bx, by;
    if (tri) {
        int f = blockIdx.x;
        {   // bijective XCD-chunk swizzle (ERRATA #11 / m204)
            int T  = (int)gridDim.x;
            int q  = T >> 3, r8 = T & 7;
            int xcd = f & 7, pos = f >> 3;
            f = (xcd < r8 ? xcd * (q + 1) : r8 * (q + 1) + (xcd - r8) * q) + pos;
        }
        int b = 0, off = 0;
        while (off + tbase + b + 1 <= f) { off += tbase + b + 1; ++b; }
        by = b; bx = f - off;
    } else {
        bx = blockIdx.x; by = blockIdx.y;
    }
    const int j0 = bx * 128;

    __shared__ __align__(16) ushort_t sA[128 * 64];
    __shared__ __align__(16) ushort_t sB[128 * 64];

    const int tid   = threadIdx.x;
    const int lane  = tid & 63;
    const int w     = tid >> 6;
    const int wr    = (w >> 1) * 64;
    const int wc    = (w & 1) * 64;
    const int l31   = lane & 31;
    const int khalf = lane >> 5;

    const ushort_t* Ab = A + (size_t)by * 128 * K;
    const ushort_t* Bb = B + (size_t)bx * 128 * K;

    f32x16 acc[2][2];
#pragma unroll
    for (int r = 0; r < 2; ++r)
#pragma unroll
        for (int c = 0; c < 2; ++c)
#pragma unroll
            for (int e = 0; e < 16; ++e) acc[r][c][e] = 0.0f;

    for (int k0 = 0; k0 < K; k0 += 64) {
#pragma unroll
        for (int qq = 0; qq < 4; ++qq) {
            int id = tid + qq * 256;           // 0..1023
            int m  = id >> 3;
            int kc = ((id & 7) ^ (m & 7)) * 8;
            unsigned lb = (unsigned)(((tid & ~63) + qq * 256) * 16);
            gload_lds16(Ab + (size_t)m * K + k0 + kc, (char*)sA + lb);
            gload_lds16(Bb + (size_t)m * K + k0 + kc, (char*)sB + lb);
        }
        __syncthreads();

#pragma unroll
        for (int h = 0; h < 4; ++h) {
            const int kq = h * 2 + khalf;
            bf16x8 fa[2], fb[2];
#pragma unroll
            for (int r = 0; r < 2; ++r) {
                int m = wr + r * 32 + l31;
                fa[r] = *(const bf16x8*)&sA[(m * 8 + (kq ^ (m & 7))) * 8];
            }
#pragma unroll
            for (int c = 0; c < 2; ++c) {
                int m = wc + c * 32 + l31;
                fb[c] = *(const bf16x8*)&sB[(m * 8 + (kq ^ (m & 7))) * 8];
            }
#pragma unroll
            for (int r = 0; r < 2; ++r)
#pragma unroll
                for (int c = 0; c < 2; ++c)
                    acc[r][c] = __builtin_amdgcn_mfma_f32_32x32x16_bf16(
                        fa[r], fb[c], acc[r][c], 0, 0, 0);
        }
        __syncthreads();
    }

    // Epilogue. 32x32 C/D layout (m74/m101): col = lane&31,
    // row = (reg&3) + 8*(reg>>2) + 4*(lane>>5). Store bf16 RNE.
#pragma unroll
    for (int r = 0; r < 2; ++r) {
#pragma unroll
        for (int c = 0; c < 2; ++c) {
            int colg = j0 + wc + c * 32 + l31;
            float bv = bias ? bias[colg] : 0.0f;
#pragma unroll
            for (int reg = 0; reg < 16; ++reg) {
                int rowl = (reg & 3) + 8 * (reg >> 2) + 4 * khalf;
                int row = by * 128 + wr + r * 32 + rowl;   // local row
                float v = acc[r][c][reg] + bv;
                unsigned u = __float_as_uint(v);
                C[(size_t)row * ldc + colg] =
                    (ushort_t)((u + 0x7FFFu + ((u >> 16) & 1u)) >> 16);
            }
        }
    }
}

// ---- fully-guarded naive fp32 NT GEMM -> f32 C (fallback only) ----
__global__ __launch_bounds__(256) void gemm_nt_naive(
    const float* __restrict__ A, const float* __restrict__ B,
    const float* __restrict__ bias, float* __restrict__ C,
    int K, int ldc, int rows, int cols)
{
    int j = blockIdx.x * 16 + (threadIdx.x & 15);
    int i = blockIdx.y * 16 + (threadIdx.x >> 4);
    if (i >= rows || j >= cols) return;
    float acc = bias ? bias[j] : 0.0f;
    const float* Ar = A + (size_t)i * K;
    const float* Br = B + (size_t)j * K;
    for (int k = 0; k < K; ++k) acc = fmaf(Ar[k], Br[k], acc);
    C[(size_t)i * ldc + j] = acc;
}

// ---- f32 -> bf16 strip cast (fallback) ----
__global__ __launch_bounds__(256) void cast_bf16_n_kernel(
    const float* __restrict__ in, ushort_t* __restrict__ out, size_t n)
{
    size_t i = (size_t)blockIdx.x * 256 + threadIdx.x;
    for (; i < n; i += (size_t)gridDim.x * 256) {
        unsigned u = __float_as_uint(in[i]);
        out[i] = (ushort_t)((u + 0x7FFFu + ((u >> 16) & 1u)) >> 16);
    }
}

// ---- threshold-pruned top-k helpers ----
__device__ __forceinline__ unsigned mono16(unsigned b) {
    return (b & 0x8000u) ? (~b & 0xFFFFu) : (b | 0x8000u);
}
__device__ __forceinline__ float inv_mono16(unsigned m) {
    unsigned b = (m & 0x8000u) ? (m & 0x7FFFu) : (~m & 0xFFFFu);
    return __uint_as_float(b << 16);
}
__device__ __forceinline__ float scrub(float v) {
    unsigned u = __float_as_uint(v);
    if (((u >> 23) & 0xFFu) == 0xFFu) return -1.0e30f;
    if (v < -1.0e37f) return -1.0e30f;
    return v;
}

// ---- r21: single-sweep, wave-autonomous top-k (k_out <= 64) ----
// One 256-thread block per row; thread t owns j = c*2048 + t*8 + e
// (reg-resident, single HBM sweep — r20 proved re-reading costs ~14us).
// Each WAVE independently: L_w = k-th largest of its 64 lane-maxima via
// 16-step ballot bisection. Per-wave correctness: if v in wave w's chunk
// is in the row's top-k, then fewer than k row values exceed v, so fewer
// than k of wave w's lane-maxima exceed v, so v >= L_w. Compaction via
// ballot+prefix-popcount into a private LDS segment (no atomics).
// ONE __syncthreads (legacy had 7), then merged rank-by-count.
__global__ __launch_bounds__(256) void topk_fast_kernel(
    const ushort_t* __restrict__ S, int N, int row_offset, int k_out,
    float* __restrict__ out_s, float* __restrict__ out_i)
{
    const int i = row_offset + blockIdx.x;
    const ushort_t* row = S + (size_t)blockIdx.x * N;
    const int t = threadIdx.x;
    const int lane = t & 63;
    const int w = t >> 6;
    const int nval = (i < N) ? i : N;
    const bool vec_ok = (N % 8) == 0;

    __shared__ unsigned cand[4][CAND_SEG];
    __shared__ unsigned scnt[4];

    // ---- single sweep: load 32 values into regs, track lane max ----
    unsigned m16[32];
    unsigned lmax = 0;
#pragma unroll
    for (int c = 0; c < 4; ++c) {
        int jb = c * 2048 + t * 8;
        if (jb < nval) {
            ushort_t vv[8];
            if (vec_ok && jb + 8 <= N) {
                *(uint4*)vv = *(const uint4*)(row + jb);
            } else {
#pragma unroll
                for (int e = 0; e < 8; ++e) vv[e] = (jb + e < N) ? row[jb + e] : 0;
            }
#pragma unroll
            for (int e = 0; e < 8; ++e) {
                unsigned m = (jb + e < nval) ? mono16(vv[e]) : 0u;
                m16[c * 8 + e] = m;
                if (m > lmax) lmax = m;
            }
        } else {
#pragma unroll
            for (int e = 0; e < 8; ++e) m16[c * 8 + e] = 0u;
        }
    }

    // ---- per-wave threshold: k-th largest of 64 lane maxima ----
    // L = max v with #lanes(lmax >= v) >= k_out; 0 if wave has < k_out
    // data lanes (early rows) -> all wave values become candidates.
    unsigned L = 0;
#pragma unroll
    for (int b = 15; b >= 0; --b) {
        unsigned cv = L | (1u << b);
        if (__popcll(__ballot(lmax >= cv)) >= k_out) L = cv;
    }

    // ---- per-wave compaction (ballot + prefix popcount, no atomics) ----
    unsigned cnt = 0;
#pragma unroll
    for (int s = 0; s < 32; ++s) {
        unsigned m = m16[s];
        bool hit = m && m >= L;
        unsigned long long bal = __ballot(hit);
        if (hit) {
            unsigned idx = cnt + (unsigned)__popcll(bal & ((1ull << lane) - 1u));
            if (idx < (unsigned)CAND_SEG) {
                int j = (s >> 3) * 2048 + t * 8 + (s & 7);
                cand[w][idx] = (m << 13) | (unsigned)(8191 - j);
            }
        }
        cnt += (unsigned)__popcll(bal);   // wave-uniform
    }
    if (lane == 0) scnt[w] = (cnt < (unsigned)CAND_SEG) ? cnt : (unsigned)CAND_SEG;
    __syncthreads();   // the ONLY block barrier

    // ---- merged rank-by-count extraction (keys unique -> ranks unique) ----
    const int c0 = (int)scnt[0], c1 = (int)scnt[1];
    const int c2 = (int)scnt[2], c3 = (int)scnt[3];
    const int m_total = c0 + c1 + c2 + c3;
    const int reals = (k_out < nval) ? k_out : nval;
    for (int c = t; c < m_total; c += 256) {
        int wseg, idx;
        if (c < c0)                { wseg = 0; idx = c; }
        else if (c < c0 + c1)      { wseg = 1; idx = c - c0; }
        else if (c < c0 + c1 + c2) { wseg = 2; idx = c - c0 - c1; }
        else                       { wseg = 3; idx = c - c0 - c1 - c2; }
        unsigned key = cand[wseg][idx];
        int rank = 0;
        for (int x = 0; x < c0; ++x) rank += (cand[0][x] > key) ? 1 : 0;
        for (int x = 0; x < c1; ++x) rank += (cand[1][x] > key) ? 1 : 0;
        for (int x = 0; x < c2; ++x) rank += (cand[2][x] > key) ? 1 : 0;
        for (int x = 0; x < c3; ++x) rank += (cand[3][x] > key) ? 1 : 0;
        if (rank < reals) {
            out_s[(size_t)i * k_out + rank] = scrub(inv_mono16(key >> 13));
            out_i[(size_t)i * k_out + rank] = (float)(8191 - (int)(key & 0x1FFFu));
        }
    }
    for (int r = reals + t; r < k_out; r += 256) {
        out_s[(size_t)i * k_out + r] = -1.0e30f;
        out_i[(size_t)i * k_out + r] = (float)r;
    }
}

// ---- legacy 256-thread top-k (fallback for k_out > 64) ----
__global__ __launch_bounds__(256) void topk_kernel(
    const ushort_t* __restrict__ S, int N, int row_offset, int k_out,
    float* __restrict__ out_s, float* __restrict__ out_i)
{
    const int i = row_offset + blockIdx.x;
    const ushort_t* row = S + (size_t)blockIdx.x * N;
    const int t = threadIdx.x;
    const int lane = t & 63;
    const int w = t >> 6;
    const int nval = (i < N) ? i : N;
    const bool vec_ok = (N % 8) == 0;

    __shared__ unsigned hist4[4][257];
    __shared__ unsigned cand[CAND_CAP];
    __shared__ unsigned cand_cnt;
    __shared__ unsigned sT1, sAbove1, sT2;

    unsigned m16[32];
    unsigned tmax = 0;
#pragma unroll
    for (int c = 0; c < 4; ++c) {
        int jb = c * 2048 + t * 8;
        if (jb < nval) {
            ushort_t vv[8];
            if (vec_ok && jb + 8 <= N) {
                *(uint4*)vv = *(const uint4*)(row + jb);
            } else {
#pragma unroll
                for (int e = 0; e < 8; ++e) vv[e] = (jb + e < N) ? row[jb + e] : 0;
            }
#pragma unroll
            for (int e = 0; e < 8; ++e) {
                unsigned m = (jb + e < nval) ? mono16(vv[e]) : 0u;
                m16[c * 8 + e] = m;
                if (m > tmax) tmax = m;
            }
        } else {
#pragma unroll
            for (int e = 0; e < 8; ++e) m16[c * 8 + e] = 0u;
        }
    }

    if (t == 0) { sT1 = 0; sAbove1 = 0; sT2 = 0; cand_cnt = 0; }
#pragma unroll
    for (int q = 0; q < 4; ++q) hist4[q][t] = 0;
    __syncthreads();

    if (tmax) atomicAdd(&hist4[w][tmax >> 8], 1u);
    __syncthreads();
    if (w == 0) {
        int base = lane * 4;
        unsigned h[4];
#pragma unroll
        for (int r = 0; r < 4; ++r)
            h[r] = hist4[0][base + r] + hist4[1][base + r] +
                   hist4[2][base + r] + hist4[3][base + r];
        unsigned lsum = h[0] + h[1] + h[2] + h[3];
        unsigned suf = lsum;
#pragma unroll
        for (int off = 1; off < 64; off <<= 1) {
            unsigned o = __shfl_down(suf, off, 64);
            suf += (lane + off < 64) ? o : 0u;
        }
        unsigned Sr[5];
        Sr[4] = suf - lsum;
#pragma unroll
        for (int r = 3; r >= 0; --r) Sr[r] = Sr[r + 1] + h[r];
#pragma unroll
        for (int r = 0; r < 4; ++r)
            if (Sr[r] >= (unsigned)k_out && Sr[r + 1] < (unsigned)k_out) {
                sT1 = (unsigned)(base + r);
                sAbove1 = Sr[r + 1];
            }
    }
    __syncthreads();
    const unsigned T1 = sT1, above1 = sAbove1;

#pragma unroll
    for (int q = 0; q < 4; ++q) hist4[q][t] = 0;
    __syncthreads();
    if (tmax && (tmax >> 8) == T1) atomicAdd(&hist4[w][tmax & 255u], 1u);
    __syncthreads();
    if (w == 0) {
        unsigned need = (unsigned)k_out - above1;
        int base = lane * 4;
        unsigned h[4];
#pragma unroll
        for (int r = 0; r < 4; ++r)
            h[r] = hist4[0][base + r] + hist4[1][base + r] +
                   hist4[2][base + r] + hist4[3][base + r];
        unsigned lsum = h[0] + h[1] + h[2] + h[3];
        unsigned suf = lsum;
#pragma unroll
        for (int off = 1; off < 64; off <<= 1) {
            unsigned o = __shfl_down(suf, off, 64);
            suf += (lane + off < 64) ? o : 0u;
        }
        unsigned Sr[5];
        Sr[4] = suf - lsum;
#pragma unroll
        for (int r = 3; r >= 0; --r) Sr[r] = Sr[r + 1] + h[r];
#pragma unroll
        for (int r = 0; r < 4; ++r)
            if (Sr[r] >= need && Sr[r + 1] < need)
                sT2 = (unsigned)(base + r);
    }
    __syncthreads();
    const unsigned Lt = (T1 << 8) | sT2;

#pragma unroll
    for (int s = 0; s < 32; ++s) {
        unsigned m = m16[s];
        if (m && m >= Lt) {
            unsigned idx = atomicAdd(&cand_cnt, 1u);
            if (idx < CAND_CAP) {
                int j = (s >> 3) * 2048 + t * 8 + (s & 7);
                cand[idx] = (m << 13) | (unsigned)(8191 - j);
            }
        }
    }
    __syncthreads();

    const int m = (cand_cnt < CAND_CAP) ? (int)cand_cnt : CAND_CAP;
    const int reals = (k_out < nval) ? k_out : nval;
    for (int c = t; c < m; c += 256) {
        unsigned key = cand[c];
        int rank = 0;
        for (int x = 0; x < m; ++x) rank += (cand[x] > key) ? 1 : 0;
        if (rank < reals) {
            out_s[(size_t)i * k_out + rank] = scrub(inv_mono16(key >> 13));
            out_i[(size_t)i * k_out + rank] = (float)(8191 - (int)(key & 0x1FFFu));
        }
    }
    for (int r = reals + t; r < k_out; r += 256) {
        out_s[(size_t)i * k_out + r] = -1.0e30f;
        out_i[(size_t)i * k_out + r] = (float)r;
    }
}

static inline void launch_topk(const ushort_t* S, int N, int r0, int rows,
                               int k_out, float* out_s, float* out_i,
                               hipStream_t stream)
{
    if (k_out <= 64)
        topk_fast_kernel<<<rows, 256, 0, stream>>>(S, N, r0, k_out, out_s, out_i);
    else
        topk_kernel<<<rows, 256, 0, stream>>>(S, N, r0, k_out, out_s, out_i);
}

extern "C" void kernel_launch(void* const* d_in, const int* in_sizes, int n_in,
                              void* d_out, int out_size, void* d_ws, size_t ws_size,
                              hipStream_t stream)
{
    const float* mentions = (const float*)d_in[0];   // [N x F]
    const float* W        = (const float*)d_in[1];   // [F x F]
    const float* bias     = (const float*)d_in[2];   // [F]

    const int F = in_sizes[2] > 0 ? in_sizes[2] : 1;
    const int N = in_sizes[0] / F;
    const int k_out = (N > 0) ? out_size / (2 * N) : 0;

    float* out_s = (float*)d_out;
    float* out_i = out_s + (size_t)N * k_out;

    prefill_kernel<<<256, 256, 0, stream>>>((float*)d_out, out_size);
    if (N <= 0 || k_out <= 0 || N > MAXN) return;

    dim3 blk(256);
    const bool tile_ok = (N % 128 == 0) && (F % 128 == 0);

    if (tile_ok) {
        // ws layout (bf16): Mb | Wb | Pb | sbuf
        ushort_t* Mb = (ushort_t*)d_ws;                    // N*F
        ushort_t* Wb = Mb + (size_t)N * F;                 // F*F
        ushort_t* Pb = Wb + (size_t)F * F;                 // N*F
        size_t fixed = ((size_t)2 * N * F + (size_t)F * F) * sizeof(ushort_t);
        size_t off = (fixed + 255) & ~(size_t)255;
        ushort_t* sbuf = (ushort_t*)((char*)d_ws + off);

        int chunk = (N < CHUNK_CAP) ? N : CHUNK_CAP;
        while (chunk > 128 && off + (size_t)chunk * N * sizeof(ushort_t) > ws_size)
            chunk >>= 1;

        if (off + (size_t)chunk * N * sizeof(ushort_t) <= ws_size) {
            cast_bf16_kernel<<<(N * F / 8 + 255) / 256, blk, 0, stream>>>(
                mentions, Mb, N * F);
            cast_bf16_kernel<<<(F * F / 8 + 255) / 256, blk, 0, stream>>>(
                W, Wb, F * F);

            // GEMM1: Pb = bf16(mentions @ W^T + b)   [N x F]  (2D grid, tri=0)
            gemm_bf16_nt<<<dim3(F / 128, N / 128), blk, 0, stream>>>(
                Mb, Wb, bias, Pb, F, F, 0, 0);

            // GEMM2 (packed triangular grid, ONE dispatch) + top-k
            for (int r0 = 0; r0 < N; r0 += chunk) {
                int rows = (N - r0 < chunk) ? (N - r0) : chunk;
                int nby = rows / 128, base = r0 / 128;
                int T = nby * base + nby * (nby + 1) / 2;   // live tiles only
                gemm_bf16_nt<<<dim3(T, 1), blk, 0, stream>>>(
                    Pb + (size_t)r0 * F, Mb, nullptr, sbuf, F, N, base, 1);
                launch_topk(sbuf, N, r0, rows, k_out, out_s, out_i, stream);
            }
            return;
        }
    }

    // ---- fallback: naive f32 GEMMs + f32->bf16 cast of the score chunk ----
    {
        float* projf = (float*)d_ws;                           // N*F f32
        size_t o1 = (((size_t)N * F * sizeof(float)) + 255) & ~(size_t)255;
        float* sf = (float*)((char*)d_ws + o1);                // chunk*N f32
        int chunk = ((N + 127) / 128) * 128;
        while (chunk > 128 &&
               o1 + (size_t)chunk * N * (sizeof(float) + sizeof(ushort_t)) > ws_size)
            chunk >>= 1;
        size_t o2 = o1 + (((size_t)chunk * N * sizeof(float) + 255) & ~(size_t)255);
        ushort_t* sb = (ushort_t*)((char*)d_ws + o2);          // chunk*N bf16

        gemm_nt_naive<<<dim3((F + 15) / 16, (N + 15) / 16), blk, 0, stream>>>(
            mentions, W, bias, projf, F, F, N, F);
        for (int r0 = 0; r0 < N; r0 += chunk) {
            int rows = (N - r0 < chunk) ? (N - r0) : chunk;
            gemm_nt_naive<<<dim3((r0 + rows + 15) / 16, (rows + 15) / 16), blk, 0, stream>>>(
                projf + (size_t)r0 * F, mentions, nullptr, sf, F, N, rows, r0 + rows);
            cast_bf16_n_kernel<<<1024, blk, 0, stream>>>(sf, sb, (size_t)rows * N);
            launch_topk(sb, N, r0, rows, k_out, out_s, out_i, stream);
        }
    }
}

// Round 14
// 239.061 us; speedup vs baseline: 1.2705x; 1.2705x over previous
//
#include <hip/hip_runtime.h>

typedef unsigned short ushort_t;
typedef __attribute__((ext_vector_type(8))) short bf16x8;    // 8 bf16 = 4 VGPRs
typedef __attribute__((ext_vector_type(16))) float f32x16;   // 32x32 MFMA acc

#define MAXN 8192
#define CAND_CAP 2048
#define CAND_SEG 512
#define CHUNK_CAP 8192   // round-15: single GEMM2 dispatch beats 2 half-size ones

// round-22 journal:
//   r18: 234.0 best (GEMM2 96.5, FETCH 181MB, conflicts 8.5M = b128 floor).
//   r19 unroll: NULL. r20 wave-topk (2 sweeps): +14us — re-read costs ~14us,
//   values must stay reg-resident.
//   r21 per-wave-threshold topk: 303.7 REGRESSION. Measured: topk 107us,
//   VALUBusy 82-86%, MfmaUtil 0, HBM 4% -> VALU-bound. Cause: k-th of 64
//   lane-maxima is LOOSE -> P(v>=L)=4.6% -> ~372 candidates (legacy ~55)
//   -> O(m^2) rank = 46x work. Barriers were never the cost.
//   r22: tight GLOBAL threshold (k-th of 256 thread-maxima, legacy-equal)
//   computed wave-redundantly: maxima -> LDS, 1 barrier, each wave bisects
//   via 4x(ballot+popc) x 16 steps (~200 VALU, no wave0-only phase).
//   Keeps: single sweep, reg-resident, atomic-free ballot compaction,
//   2 barriers total (legacy 7). Candidates ~55 -> extraction trivial.

// ---- zero-prefill d_out (safety) ----
__global__ void prefill_kernel(float* __restrict__ out, int n) {
    for (int i = blockIdx.x * 256 + threadIdx.x; i < n; i += gridDim.x * 256)
        out[i] = 0.0f;
}

// ---- f32 -> bf16 cast (RNE), 8/thread ----
__global__ __launch_bounds__(256) void cast_bf16_kernel(
    const float* __restrict__ in, ushort_t* __restrict__ out, int n)
{
    int i = (blockIdx.x * 256 + threadIdx.x) * 8;
    if (i >= n) return;
    ushort_t o[8];
#pragma unroll
    for (int q = 0; q < 8; ++q) {
        unsigned u = __float_as_uint(in[i + q]);
        o[q] = (ushort_t)((u + 0x7FFFu + ((u >> 16) & 1u)) >> 16);
    }
    *(ushort4*)(out + i)     = make_ushort4(o[0], o[1], o[2], o[3]);
    *(ushort4*)(out + i + 4) = make_ushort4(o[4], o[5], o[6], o[7]);
}

// async global->LDS, 16B per lane; lds dest = wave-uniform base + lane*16
__device__ __forceinline__ void gload_lds16(const ushort_t* g, void* lds) {
    __builtin_amdgcn_global_load_lds(
        (const __attribute__((address_space(1))) unsigned int*)g,
        (__attribute__((address_space(3))) unsigned int*)lds, 16, 0, 0);
}

// ---- bf16 MFMA NT GEMM: C[i][j] = bf16(sum_k A[i][k]*B[j][k] (+bias[j])) ----
// 128x128 block tile, BK=64, 4 waves 2x2; wave tile 64x64 = 2x2 of 32x32x16.
// __launch_bounds__(256,4) -> 4 blocks/CU.
// tri=1: PACKED triangular grid — blockIdx.x flat over live tiles only,
// with bijective XCD-chunk swizzle (m204) — r18: FETCH 224->181MB, keep.
// LDS 16B-slot swizzle: slot(m,kq) = m*8 + (kq ^ (m&7))  [conflict floor:
// residual 8.5M SQ_LDS_BANK_CONFLICT = inherent 2-way b128 aliasing, free].
__global__ __launch_bounds__(256, 4) void gemm_bf16_nt(
    const ushort_t* __restrict__ A, const ushort_t* __restrict__ B,
    const float* __restrict__ bias, ushort_t* __restrict__ C,
    int K, int ldc, int tbase, int tri)
{
    int bx, by;
    if (tri) {
        int f = blockIdx.x;
        {   // bijective XCD-chunk swizzle (ERRATA #11 / m204)
            int T  = (int)gridDim.x;
            int q  = T >> 3, r8 = T & 7;
            int xcd = f & 7, pos = f >> 3;
            f = (xcd < r8 ? xcd * (q + 1) : r8 * (q + 1) + (xcd - r8) * q) + pos;
        }
        int b = 0, off = 0;
        while (off + tbase + b + 1 <= f) { off += tbase + b + 1; ++b; }
        by = b; bx = f - off;
    } else {
        bx = blockIdx.x; by = blockIdx.y;
    }
    const int j0 = bx * 128;

    __shared__ __align__(16) ushort_t sA[128 * 64];
    __shared__ __align__(16) ushort_t sB[128 * 64];

    const int tid   = threadIdx.x;
    const int lane  = tid & 63;
    const int w     = tid >> 6;
    const int wr    = (w >> 1) * 64;
    const int wc    = (w & 1) * 64;
    const int l31   = lane & 31;
    const int khalf = lane >> 5;

    const ushort_t* Ab = A + (size_t)by * 128 * K;
    const ushort_t* Bb = B + (size_t)bx * 128 * K;

    f32x16 acc[2][2];
#pragma unroll
    for (int r = 0; r < 2; ++r)
#pragma unroll
        for (int c = 0; c < 2; ++c)
#pragma unroll
            for (int e = 0; e < 16; ++e) acc[r][c][e] = 0.0f;

    for (int k0 = 0; k0 < K; k0 += 64) {
#pragma unroll
        for (int qq = 0; qq < 4; ++qq) {
            int id = tid + qq * 256;           // 0..1023
            int m  = id >> 3;
            int kc = ((id & 7) ^ (m & 7)) * 8;
            unsigned lb = (unsigned)(((tid & ~63) + qq * 256) * 16);
            gload_lds16(Ab + (size_t)m * K + k0 + kc, (char*)sA + lb);
            gload_lds16(Bb + (size_t)m * K + k0 + kc, (char*)sB + lb);
        }
        __syncthreads();

#pragma unroll
        for (int h = 0; h < 4; ++h) {
            const int kq = h * 2 + khalf;
            bf16x8 fa[2], fb[2];
#pragma unroll
            for (int r = 0; r < 2; ++r) {
                int m = wr + r * 32 + l31;
                fa[r] = *(const bf16x8*)&sA[(m * 8 + (kq ^ (m & 7))) * 8];
            }
#pragma unroll
            for (int c = 0; c < 2; ++c) {
                int m = wc + c * 32 + l31;
                fb[c] = *(const bf16x8*)&sB[(m * 8 + (kq ^ (m & 7))) * 8];
            }
#pragma unroll
            for (int r = 0; r < 2; ++r)
#pragma unroll
                for (int c = 0; c < 2; ++c)
                    acc[r][c] = __builtin_amdgcn_mfma_f32_32x32x16_bf16(
                        fa[r], fb[c], acc[r][c], 0, 0, 0);
        }
        __syncthreads();
    }

    // Epilogue. 32x32 C/D layout (m74/m101): col = lane&31,
    // row = (reg&3) + 8*(reg>>2) + 4*(lane>>5). Store bf16 RNE.
#pragma unroll
    for (int r = 0; r < 2; ++r) {
#pragma unroll
        for (int c = 0; c < 2; ++c) {
            int colg = j0 + wc + c * 32 + l31;
            float bv = bias ? bias[colg] : 0.0f;
#pragma unroll
            for (int reg = 0; reg < 16; ++reg) {
                int rowl = (reg & 3) + 8 * (reg >> 2) + 4 * khalf;
                int row = by * 128 + wr + r * 32 + rowl;   // local row
                float v = acc[r][c][reg] + bv;
                unsigned u = __float_as_uint(v);
                C[(size_t)row * ldc + colg] =
                    (ushort_t)((u + 0x7FFFu + ((u >> 16) & 1u)) >> 16);
            }
        }
    }
}

// ---- fully-guarded naive fp32 NT GEMM -> f32 C (fallback only) ----
__global__ __launch_bounds__(256) void gemm_nt_naive(
    const float* __restrict__ A, const float* __restrict__ B,
    const float* __restrict__ bias, float* __restrict__ C,
    int K, int ldc, int rows, int cols)
{
    int j = blockIdx.x * 16 + (threadIdx.x & 15);
    int i = blockIdx.y * 16 + (threadIdx.x >> 4);
    if (i >= rows || j >= cols) return;
    float acc = bias ? bias[j] : 0.0f;
    const float* Ar = A + (size_t)i * K;
    const float* Br = B + (size_t)j * K;
    for (int k = 0; k < K; ++k) acc = fmaf(Ar[k], Br[k], acc);
    C[(size_t)i * ldc + j] = acc;
}

// ---- f32 -> bf16 strip cast (fallback) ----
__global__ __launch_bounds__(256) void cast_bf16_n_kernel(
    const float* __restrict__ in, ushort_t* __restrict__ out, size_t n)
{
    size_t i = (size_t)blockIdx.x * 256 + threadIdx.x;
    for (; i < n; i += (size_t)gridDim.x * 256) {
        unsigned u = __float_as_uint(in[i]);
        out[i] = (ushort_t)((u + 0x7FFFu + ((u >> 16) & 1u)) >> 16);
    }
}

// ---- threshold-pruned top-k helpers ----
__device__ __forceinline__ unsigned mono16(unsigned b) {
    return (b & 0x8000u) ? (~b & 0xFFFFu) : (b | 0x8000u);
}
__device__ __forceinline__ float inv_mono16(unsigned m) {
    unsigned b = (m & 0x8000u) ? (m & 0x7FFFu) : (~m & 0xFFFFu);
    return __uint_as_float(b << 16);
}
__device__ __forceinline__ float scrub(float v) {
    unsigned u = __float_as_uint(v);
    if (((u >> 23) & 0xFFu) == 0xFFu) return -1.0e30f;
    if (v < -1.0e37f) return -1.0e30f;
    return v;
}

// ---- r22: single-sweep top-k, tight global threshold, 2 barriers ----
// One 256-thread block per row; thread t owns j = c*2048 + t*8 + e,
// values reg-resident (r20: re-reading costs ~14us).
// Threshold = k-th largest of the 256 THREAD-maxima (tight, legacy-equal;
// r21's per-wave k-th-of-64 gave 7x candidates -> 46x rank work, 107us
// VALU-bound). Computed WAVE-REDUNDANTLY: maxima -> LDS, one barrier,
// each lane holds 4 maxima, 16-step bisection where count(>=cv) =
// sum of 4x popcll(ballot) — no wave0-only phase, no extra barriers.
// Guarantee: >=k threads have max >= Lt, each contributes >=1 candidate
// >= Lt => count >= k. Compaction: per-wave ballot+prefix (atomic-free)
// into private segments; expected ~55 total candidates (~14/wave << 512).
__global__ __launch_bounds__(256) void topk_fast_kernel(
    const ushort_t* __restrict__ S, int N, int row_offset, int k_out,
    float* __restrict__ out_s, float* __restrict__ out_i)
{
    const int i = row_offset + blockIdx.x;
    const ushort_t* row = S + (size_t)blockIdx.x * N;
    const int t = threadIdx.x;
    const int lane = t & 63;
    const int w = t >> 6;
    const int nval = (i < N) ? i : N;
    const bool vec_ok = (N % 8) == 0;

    __shared__ unsigned smax[256];
    __shared__ unsigned cand[4][CAND_SEG];
    __shared__ unsigned scnt[4];

    // ---- single sweep: 32 values into regs, track thread max ----
    unsigned m16[32];
    unsigned tmax = 0;
#pragma unroll
    for (int c = 0; c < 4; ++c) {
        int jb = c * 2048 + t * 8;
        if (jb < nval) {
            ushort_t vv[8];
            if (vec_ok && jb + 8 <= N) {
                *(uint4*)vv = *(const uint4*)(row + jb);
            } else {
#pragma unroll
                for (int e = 0; e < 8; ++e) vv[e] = (jb + e < N) ? row[jb + e] : 0;
            }
#pragma unroll
            for (int e = 0; e < 8; ++e) {
                unsigned m = (jb + e < nval) ? mono16(vv[e]) : 0u;
                m16[c * 8 + e] = m;
                if (m > tmax) tmax = m;
            }
        } else {
#pragma unroll
            for (int e = 0; e < 8; ++e) m16[c * 8 + e] = 0u;
        }
    }
    smax[t] = tmax;
    __syncthreads();   // barrier 1: maxima visible block-wide

    // ---- global threshold, computed redundantly by every wave ----
    // Lt = max v with #threads(tmax >= v) >= k_out (0 if < k_out have data)
    const unsigned v0 = smax[lane];
    const unsigned v1 = smax[lane + 64];
    const unsigned v2 = smax[lane + 128];
    const unsigned v3 = smax[lane + 192];
    unsigned Lt = 0;
#pragma unroll
    for (int b = 15; b >= 0; --b) {
        unsigned cv = Lt | (1u << b);
        unsigned cnt = (unsigned)__popcll(__ballot(v0 >= cv))
                     + (unsigned)__popcll(__ballot(v1 >= cv))
                     + (unsigned)__popcll(__ballot(v2 >= cv))
                     + (unsigned)__popcll(__ballot(v3 >= cv));
        if (cnt >= (unsigned)k_out) Lt = cv;
    }

    // ---- per-wave compaction (ballot + prefix popcount, no atomics) ----
    unsigned cnt = 0;
#pragma unroll
    for (int s = 0; s < 32; ++s) {
        unsigned m = m16[s];
        bool hit = m && m >= Lt;
        unsigned long long bal = __ballot(hit);
        if (hit) {
            unsigned idx = cnt + (unsigned)__popcll(bal & ((1ull << lane) - 1u));
            if (idx < (unsigned)CAND_SEG) {
                int j = (s >> 3) * 2048 + t * 8 + (s & 7);
                cand[w][idx] = (m << 13) | (unsigned)(8191 - j);
            }
        }
        cnt += (unsigned)__popcll(bal);   // wave-uniform
    }
    if (lane == 0) scnt[w] = (cnt < (unsigned)CAND_SEG) ? cnt : (unsigned)CAND_SEG;
    __syncthreads();   // barrier 2: candidates visible

    // ---- merged rank-by-count extraction (keys unique -> ranks unique) ----
    const int c0 = (int)scnt[0], c1 = (int)scnt[1];
    const int c2 = (int)scnt[2], c3 = (int)scnt[3];
    const int m_total = c0 + c1 + c2 + c3;
    const int reals = (k_out < nval) ? k_out : nval;
    for (int c = t; c < m_total; c += 256) {
        int wseg, idx;
        if (c < c0)                { wseg = 0; idx = c; }
        else if (c < c0 + c1)      { wseg = 1; idx = c - c0; }
        else if (c < c0 + c1 + c2) { wseg = 2; idx = c - c0 - c1; }
        else                       { wseg = 3; idx = c - c0 - c1 - c2; }
        unsigned key = cand[wseg][idx];
        int rank = 0;
        for (int x = 0; x < c0; ++x) rank += (cand[0][x] > key) ? 1 : 0;
        for (int x = 0; x < c1; ++x) rank += (cand[1][x] > key) ? 1 : 0;
        for (int x = 0; x < c2; ++x) rank += (cand[2][x] > key) ? 1 : 0;
        for (int x = 0; x < c3; ++x) rank += (cand[3][x] > key) ? 1 : 0;
        if (rank < reals) {
            out_s[(size_t)i * k_out + rank] = scrub(inv_mono16(key >> 13));
            out_i[(size_t)i * k_out + rank] = (float)(8191 - (int)(key & 0x1FFFu));
        }
    }
    for (int r = reals + t; r < k_out; r += 256) {
        out_s[(size_t)i * k_out + r] = -1.0e30f;
        out_i[(size_t)i * k_out + r] = (float)r;
    }
}

// ---- legacy 256-thread top-k (fallback for k_out > 64) ----
__global__ __launch_bounds__(256) void topk_kernel(
    const ushort_t* __restrict__ S, int N, int row_offset, int k_out,
    float* __restrict__ out_s, float* __restrict__ out_i)
{
    const int i = row_offset + blockIdx.x;
    const ushort_t* row = S + (size_t)blockIdx.x * N;
    const int t = threadIdx.x;
    const int lane = t & 63;
    const int w = t >> 6;
    const int nval = (i < N) ? i : N;
    const bool vec_ok = (N % 8) == 0;

    __shared__ unsigned hist4[4][257];
    __shared__ unsigned cand[CAND_CAP];
    __shared__ unsigned cand_cnt;
    __shared__ unsigned sT1, sAbove1, sT2;

    unsigned m16[32];
    unsigned tmax = 0;
#pragma unroll
    for (int c = 0; c < 4; ++c) {
        int jb = c * 2048 + t * 8;
        if (jb < nval) {
            ushort_t vv[8];
            if (vec_ok && jb + 8 <= N) {
                *(uint4*)vv = *(const uint4*)(row + jb);
            } else {
#pragma unroll
                for (int e = 0; e < 8; ++e) vv[e] = (jb + e < N) ? row[jb + e] : 0;
            }
#pragma unroll
            for (int e = 0; e < 8; ++e) {
                unsigned m = (jb + e < nval) ? mono16(vv[e]) : 0u;
                m16[c * 8 + e] = m;
                if (m > tmax) tmax = m;
            }
        } else {
#pragma unroll
            for (int e = 0; e < 8; ++e) m16[c * 8 + e] = 0u;
        }
    }

    if (t == 0) { sT1 = 0; sAbove1 = 0; sT2 = 0; cand_cnt = 0; }
#pragma unroll
    for (int q = 0; q < 4; ++q) hist4[q][t] = 0;
    __syncthreads();

    if (tmax) atomicAdd(&hist4[w][tmax >> 8], 1u);
    __syncthreads();
    if (w == 0) {
        int base = lane * 4;
        unsigned h[4];
#pragma unroll
        for (int r = 0; r < 4; ++r)
            h[r] = hist4[0][base + r] + hist4[1][base + r] +
                   hist4[2][base + r] + hist4[3][base + r];
        unsigned lsum = h[0] + h[1] + h[2] + h[3];
        unsigned suf = lsum;
#pragma unroll
        for (int off = 1; off < 64; off <<= 1) {
            unsigned o = __shfl_down(suf, off, 64);
            suf += (lane + off < 64) ? o : 0u;
        }
        unsigned Sr[5];
        Sr[4] = suf - lsum;
#pragma unroll
        for (int r = 3; r >= 0; --r) Sr[r] = Sr[r + 1] + h[r];
#pragma unroll
        for (int r = 0; r < 4; ++r)
            if (Sr[r] >= (unsigned)k_out && Sr[r + 1] < (unsigned)k_out) {
                sT1 = (unsigned)(base + r);
                sAbove1 = Sr[r + 1];
            }
    }
    __syncthreads();
    const unsigned T1 = sT1, above1 = sAbove1;

#pragma unroll
    for (int q = 0; q < 4; ++q) hist4[q][t] = 0;
    __syncthreads();
    if (tmax && (tmax >> 8) == T1) atomicAdd(&hist4[w][tmax & 255u], 1u);
    __syncthreads();
    if (w == 0) {
        unsigned need = (unsigned)k_out - above1;
        int base = lane * 4;
        unsigned h[4];
#pragma unroll
        for (int r = 0; r < 4; ++r)
            h[r] = hist4[0][base + r] + hist4[1][base + r] +
                   hist4[2][base + r] + hist4[3][base + r];
        unsigned lsum = h[0] + h[1] + h[2] + h[3];
        unsigned suf = lsum;
#pragma unroll
        for (int off = 1; off < 64; off <<= 1) {
            unsigned o = __shfl_down(suf, off, 64);
            suf += (lane + off < 64) ? o : 0u;
        }
        unsigned Sr[5];
        Sr[4] = suf - lsum;
#pragma unroll
        for (int r = 3; r >= 0; --r) Sr[r] = Sr[r + 1] + h[r];
#pragma unroll
        for (int r = 0; r < 4; ++r)
            if (Sr[r] >= need && Sr[r + 1] < need)
                sT2 = (unsigned)(base + r);
    }
    __syncthreads();
    const unsigned Lt = (T1 << 8) | sT2;

#pragma unroll
    for (int s = 0; s < 32; ++s) {
        unsigned m = m16[s];
        if (m && m >= Lt) {
            unsigned idx = atomicAdd(&cand_cnt, 1u);
            if (idx < CAND_CAP) {
                int j = (s >> 3) * 2048 + t * 8 + (s & 7);
                cand[idx] = (m << 13) | (unsigned)(8191 - j);
            }
        }
    }
    __syncthreads();

    const int m = (cand_cnt < CAND_CAP) ? (int)cand_cnt : CAND_CAP;
    const int reals = (k_out < nval) ? k_out : nval;
    for (int c = t; c < m; c += 256) {
        unsigned key = cand[c];
        int rank = 0;
        for (int x = 0; x < m; ++x) rank += (cand[x] > key) ? 1 : 0;
        if (rank < reals) {
            out_s[(size_t)i * k_out + rank] = scrub(inv_mono16(key >> 13));
            out_i[(size_t)i * k_out + rank] = (float)(8191 - (int)(key & 0x1FFFu));
        }
    }
    for (int r = reals + t; r < k_out; r += 256) {
        out_s[(size_t)i * k_out + r] = -1.0e30f;
        out_i[(size_t)i * k_out + r] = (float)r;
    }
}

static inline void launch_topk(const ushort_t* S, int N, int r0, int rows,
                               int k_out, float* out_s, float* out_i,
                               hipStream_t stream)
{
    if (k_out <= 64)
        topk_fast_kernel<<<rows, 256, 0, stream>>>(S, N, r0, k_out, out_s, out_i);
    else
        topk_kernel<<<rows, 256, 0, stream>>>(S, N, r0, k_out, out_s, out_i);
}

extern "C" void kernel_launch(void* const* d_in, const int* in_sizes, int n_in,
                              void* d_out, int out_size, void* d_ws, size_t ws_size,
                              hipStream_t stream)
{
    const float* mentions = (const float*)d_in[0];   // [N x F]
    const float* W        = (const float*)d_in[1];   // [F x F]
    const float* bias     = (const float*)d_in[2];   // [F]

    const int F = in_sizes[2] > 0 ? in_sizes[2] : 1;
    const int N = in_sizes[0] / F;
    const int k_out = (N > 0) ? out_size / (2 * N) : 0;

    float* out_s = (float*)d_out;
    float* out_i = out_s + (size_t)N * k_out;

    prefill_kernel<<<256, 256, 0, stream>>>((float*)d_out, out_size);
    if (N <= 0 || k_out <= 0 || N > MAXN) return;

    dim3 blk(256);
    const bool tile_ok = (N % 128 == 0) && (F % 128 == 0);

    if (tile_ok) {
        // ws layout (bf16): Mb | Wb | Pb | sbuf
        ushort_t* Mb = (ushort_t*)d_ws;                    // N*F
        ushort_t* Wb = Mb + (size_t)N * F;                 // F*F
        ushort_t* Pb = Wb + (size_t)F * F;                 // N*F
        size_t fixed = ((size_t)2 * N * F + (size_t)F * F) * sizeof(ushort_t);
        size_t off = (fixed + 255) & ~(size_t)255;
        ushort_t* sbuf = (ushort_t*)((char*)d_ws + off);

        int chunk = (N < CHUNK_CAP) ? N : CHUNK_CAP;
        while (chunk > 128 && off + (size_t)chunk * N * sizeof(ushort_t) > ws_size)
            chunk >>= 1;

        if (off + (size_t)chunk * N * sizeof(ushort_t) <= ws_size) {
            cast_bf16_kernel<<<(N * F / 8 + 255) / 256, blk, 0, stream>>>(
                mentions, Mb, N * F);
            cast_bf16_kernel<<<(F * F / 8 + 255) / 256, blk, 0, stream>>>(
                W, Wb, F * F);

            // GEMM1: Pb = bf16(mentions @ W^T + b)   [N x F]  (2D grid, tri=0)
            gemm_bf16_nt<<<dim3(F / 128, N / 128), blk, 0, stream>>>(
                Mb, Wb, bias, Pb, F, F, 0, 0);

            // GEMM2 (packed triangular grid, ONE dispatch) + top-k
            for (int r0 = 0; r0 < N; r0 += chunk) {
                int rows = (N - r0 < chunk) ? (N - r0) : chunk;
                int nby = rows / 128, base = r0 / 128;
                int T = nby * base + nby * (nby + 1) / 2;   // live tiles only
                gemm_bf16_nt<<<dim3(T, 1), blk, 0, stream>>>(
                    Pb + (size_t)r0 * F, Mb, nullptr, sbuf, F, N, base, 1);
                launch_topk(sbuf, N, r0, rows, k_out, out_s, out_i, stream);
            }
            return;
        }
    }

    // ---- fallback: naive f32 GEMMs + f32->bf16 cast of the score chunk ----
    {
        float* projf = (float*)d_ws;                           // N*F f32
        size_t o1 = (((size_t)N * F * sizeof(float)) + 255) & ~(size_t)255;
        float* sf = (float*)((char*)d_ws + o1);                // chunk*N f32
        int chunk = ((N + 127) / 128) * 128;
        while (chunk > 128 &&
               o1 + (size_t)chunk * N * (sizeof(float) + sizeof(ushort_t)) > ws_size)
            chunk >>= 1;
        size_t o2 = o1 + (((size_t)chunk * N * sizeof(float) + 255) & ~(size_t)255);
        ushort_t* sb = (ushort_t*)((char*)d_ws + o2);          // chunk*N bf16

        gemm_nt_naive<<<dim3((F + 15) / 16, (N + 15) / 16), blk, 0, stream>>>(
            mentions, W, bias, projf, F, F, N, F);
        for (int r0 = 0; r0 < N; r0 += chunk) {
            int rows = (N - r0 < chunk) ? (N - r0) : chunk;
            gemm_nt_naive<<<dim3((r0 + rows + 15) / 16, (rows + 15) / 16), blk, 0, stream>>>(
                projf + (size_t)r0 * F, mentions, nullptr, sf, F, N, rows, r0 + rows);
            cast_bf16_n_kernel<<<1024, blk, 0, stream>>>(sf, sb, (size_t)rows * N);
            launch_topk(sb, N, r0, rows, k_out, out_s, out_i, stream);
        }
    }
}

// Round 15
// 238.775 us; speedup vs baseline: 1.2721x; 1.0012x over previous
//
#include <hip/hip_runtime.h>

typedef unsigned short ushort_t;
typedef __attribute__((ext_vector_type(8))) short bf16x8;    // 8 bf16 = 4 VGPRs
typedef __attribute__((ext_vector_type(16))) float f32x16;   // 32x32 MFMA acc

#define MAXN 8192
#define CAND_CAP 2048
#define CHUNK_CAP 8192   // round-15: single GEMM2 dispatch beats 2 half-size ones

// round-23 journal:
//   Budget model CORRECTED via r21's direct topk measurement (107us):
//     GEMM2 96.6 | GEMM1 ~88 (!) | topk_legacy ~37 | casts+prefill ~11
//   (consistent across r16/r17/r19/r21/r22 residuals). GEMM1 = 200 TF at
//   512 blocks = 2 blocks/CU — no cross-block overlap (m114 needs >=4),
//   barrier-drain fully exposed. topk was NEVER the hog; r20-r22 arc
//   (wave topk, per-wave thresholds, global-bisect) never beat legacy ->
//   topk REVERTED to legacy.
//   r23 single new variable: gemm1_bf16_nt — 64x128 tile (wave-tile 32x64,
//   acc[2], 24KB LDS, same swizzle/fragment/epilogue machinery) -> grid
//   (8,128) = 1024 blocks = exactly 4/CU. GEMM2 kernel byte-identical.
//   Predict: GEMM1 88 -> ~35-45, total 233 -> ~185-195.

// ---- zero-prefill d_out (safety) ----
__global__ void prefill_kernel(float* __restrict__ out, int n) {
    for (int i = blockIdx.x * 256 + threadIdx.x; i < n; i += gridDim.x * 256)
        out[i] = 0.0f;
}

// ---- f32 -> bf16 cast (RNE), 8/thread ----
__global__ __launch_bounds__(256) void cast_bf16_kernel(
    const float* __restrict__ in, ushort_t* __restrict__ out, int n)
{
    int i = (blockIdx.x * 256 + threadIdx.x) * 8;
    if (i >= n) return;
    ushort_t o[8];
#pragma unroll
    for (int q = 0; q < 8; ++q) {
        unsigned u = __float_as_uint(in[i + q]);
        o[q] = (ushort_t)((u + 0x7FFFu + ((u >> 16) & 1u)) >> 16);
    }
    *(ushort4*)(out + i)     = make_ushort4(o[0], o[1], o[2], o[3]);
    *(ushort4*)(out + i + 4) = make_ushort4(o[4], o[5], o[6], o[7]);
}

// async global->LDS, 16B per lane; lds dest = wave-uniform base + lane*16
__device__ __forceinline__ void gload_lds16(const ushort_t* g, void* lds) {
    __builtin_amdgcn_global_load_lds(
        (const __attribute__((address_space(1))) unsigned int*)g,
        (__attribute__((address_space(3))) unsigned int*)lds, 16, 0, 0);
}

// ---- bf16 MFMA NT GEMM: C[i][j] = bf16(sum_k A[i][k]*B[j][k] (+bias[j])) ----
// 128x128 block tile, BK=64, 4 waves 2x2; wave tile 64x64 = 2x2 of 32x32x16.
// __launch_bounds__(256,4) -> 4 blocks/CU.
// tri=1: PACKED triangular grid — blockIdx.x flat over live tiles only,
// with bijective XCD-chunk swizzle (m204) — r18: FETCH 224->181MB, keep.
// LDS 16B-slot swizzle: slot(m,kq) = m*8 + (kq ^ (m&7))  [conflict floor:
// residual 8.5M SQ_LDS_BANK_CONFLICT = inherent 2-way b128 aliasing, free].
__global__ __launch_bounds__(256, 4) void gemm_bf16_nt(
    const ushort_t* __restrict__ A, const ushort_t* __restrict__ B,
    const float* __restrict__ bias, ushort_t* __restrict__ C,
    int K, int ldc, int tbase, int tri)
{
    int bx, by;
    if (tri) {
        int f = blockIdx.x;
        {   // bijective XCD-chunk swizzle (ERRATA #11 / m204)
            int T  = (int)gridDim.x;
            int q  = T >> 3, r8 = T & 7;
            int xcd = f & 7, pos = f >> 3;
            f = (xcd < r8 ? xcd * (q + 1) : r8 * (q + 1) + (xcd - r8) * q) + pos;
        }
        int b = 0, off = 0;
        while (off + tbase + b + 1 <= f) { off += tbase + b + 1; ++b; }
        by = b; bx = f - off;
    } else {
        bx = blockIdx.x; by = blockIdx.y;
    }
    const int j0 = bx * 128;

    __shared__ __align__(16) ushort_t sA[128 * 64];
    __shared__ __align__(16) ushort_t sB[128 * 64];

    const int tid   = threadIdx.x;
    const int lane  = tid & 63;
    const int w     = tid >> 6;
    const int wr    = (w >> 1) * 64;
    const int wc    = (w & 1) * 64;
    const int l31   = lane & 31;
    const int khalf = lane >> 5;

    const ushort_t* Ab = A + (size_t)by * 128 * K;
    const ushort_t* Bb = B + (size_t)bx * 128 * K;

    f32x16 acc[2][2];
#pragma unroll
    for (int r = 0; r < 2; ++r)
#pragma unroll
        for (int c = 0; c < 2; ++c)
#pragma unroll
            for (int e = 0; e < 16; ++e) acc[r][c][e] = 0.0f;

    for (int k0 = 0; k0 < K; k0 += 64) {
#pragma unroll
        for (int qq = 0; qq < 4; ++qq) {
            int id = tid + qq * 256;           // 0..1023
            int m  = id >> 3;
            int kc = ((id & 7) ^ (m & 7)) * 8;
            unsigned lb = (unsigned)(((tid & ~63) + qq * 256) * 16);
            gload_lds16(Ab + (size_t)m * K + k0 + kc, (char*)sA + lb);
            gload_lds16(Bb + (size_t)m * K + k0 + kc, (char*)sB + lb);
        }
        __syncthreads();

#pragma unroll
        for (int h = 0; h < 4; ++h) {
            const int kq = h * 2 + khalf;
            bf16x8 fa[2], fb[2];
#pragma unroll
            for (int r = 0; r < 2; ++r) {
                int m = wr + r * 32 + l31;
                fa[r] = *(const bf16x8*)&sA[(m * 8 + (kq ^ (m & 7))) * 8];
            }
#pragma unroll
            for (int c = 0; c < 2; ++c) {
                int m = wc + c * 32 + l31;
                fb[c] = *(const bf16x8*)&sB[(m * 8 + (kq ^ (m & 7))) * 8];
            }
#pragma unroll
            for (int r = 0; r < 2; ++r)
#pragma unroll
                for (int c = 0; c < 2; ++c)
                    acc[r][c] = __builtin_amdgcn_mfma_f32_32x32x16_bf16(
                        fa[r], fb[c], acc[r][c], 0, 0, 0);
        }
        __syncthreads();
    }

    // Epilogue. 32x32 C/D layout (m74/m101): col = lane&31,
    // row = (reg&3) + 8*(reg>>2) + 4*(lane>>5). Store bf16 RNE.
#pragma unroll
    for (int r = 0; r < 2; ++r) {
#pragma unroll
        for (int c = 0; c < 2; ++c) {
            int colg = j0 + wc + c * 32 + l31;
            float bv = bias ? bias[colg] : 0.0f;
#pragma unroll
            for (int reg = 0; reg < 16; ++reg) {
                int rowl = (reg & 3) + 8 * (reg >> 2) + 4 * khalf;
                int row = by * 128 + wr + r * 32 + rowl;   // local row
                float v = acc[r][c][reg] + bv;
                unsigned u = __float_as_uint(v);
                C[(size_t)row * ldc + colg] =
                    (ushort_t)((u + 0x7FFFu + ((u >> 16) & 1u)) >> 16);
            }
        }
    }
}

// ---- r23: GEMM1 variant — 64x128 block tile for 4 blocks/CU at 512->1024
// blocks. Wave tile 32x64 (1x2 of 32x32x16), acc[2] (32 AGPR), LDS 24KB
// (sA 64x64 + sB 128x64). Same staging pattern (pre-swizzled source,
// linear LDS dest), same slot(m,kq)=m*8+(kq^(m&7)) swizzle, same fragment
// reads and verified C/D epilogue mapping with r fixed to 0.
__global__ __launch_bounds__(256, 4) void gemm1_bf16_nt(
    const ushort_t* __restrict__ A, const ushort_t* __restrict__ B,
    const float* __restrict__ bias, ushort_t* __restrict__ C,
    int K, int ldc)
{
    const int bx = blockIdx.x;       // col tile: F/128
    const int by = blockIdx.y;       // row tile: N/64
    const int j0 = bx * 128;

    __shared__ __align__(16) ushort_t sA[64 * 64];
    __shared__ __align__(16) ushort_t sB[128 * 64];

    const int tid   = threadIdx.x;
    const int lane  = tid & 63;
    const int w     = tid >> 6;
    const int wr    = (w >> 1) * 32;     // 0 / 32
    const int wc    = (w & 1) * 64;      // 0 / 64
    const int l31   = lane & 31;
    const int khalf = lane >> 5;

    const ushort_t* Ab = A + (size_t)by * 64 * K;
    const ushort_t* Bb = B + (size_t)bx * 128 * K;

    f32x16 acc[2];
#pragma unroll
    for (int c = 0; c < 2; ++c)
#pragma unroll
        for (int e = 0; e < 16; ++e) acc[c][e] = 0.0f;

    for (int k0 = 0; k0 < K; k0 += 64) {
#pragma unroll
        for (int qq = 0; qq < 2; ++qq) {   // sA: 512 lane-loads
            int id = tid + qq * 256;       // 0..511 -> m 0..63
            int m  = id >> 3;
            int kc = ((id & 7) ^ (m & 7)) * 8;
            unsigned lb = (unsigned)(((tid & ~63) + qq * 256) * 16);
            gload_lds16(Ab + (size_t)m * K + k0 + kc, (char*)sA + lb);
        }
#pragma unroll
        for (int qq = 0; qq < 4; ++qq) {   // sB: 1024 lane-loads
            int id = tid + qq * 256;       // 0..1023 -> m 0..127
            int m  = id >> 3;
            int kc = ((id & 7) ^ (m & 7)) * 8;
            unsigned lb = (unsigned)(((tid & ~63) + qq * 256) * 16);
            gload_lds16(Bb + (size_t)m * K + k0 + kc, (char*)sB + lb);
        }
        __syncthreads();

#pragma unroll
        for (int h = 0; h < 4; ++h) {
            const int kq = h * 2 + khalf;
            bf16x8 fa, fb[2];
            {
                int m = wr + l31;
                fa = *(const bf16x8*)&sA[(m * 8 + (kq ^ (m & 7))) * 8];
            }
#pragma unroll
            for (int c = 0; c < 2; ++c) {
                int m = wc + c * 32 + l31;
                fb[c] = *(const bf16x8*)&sB[(m * 8 + (kq ^ (m & 7))) * 8];
            }
#pragma unroll
            for (int c = 0; c < 2; ++c)
                acc[c] = __builtin_amdgcn_mfma_f32_32x32x16_bf16(
                    fa, fb[c], acc[c], 0, 0, 0);
        }
        __syncthreads();
    }

#pragma unroll
    for (int c = 0; c < 2; ++c) {
        int colg = j0 + wc + c * 32 + l31;
        float bv = bias ? bias[colg] : 0.0f;
#pragma unroll
        for (int reg = 0; reg < 16; ++reg) {
            int rowl = (reg & 3) + 8 * (reg >> 2) + 4 * khalf;
            int row = by * 64 + wr + rowl;
            float v = acc[c][reg] + bv;
            unsigned u = __float_as_uint(v);
            C[(size_t)row * ldc + colg] =
                (ushort_t)((u + 0x7FFFu + ((u >> 16) & 1u)) >> 16);
        }
    }
}

// ---- fully-guarded naive fp32 NT GEMM -> f32 C (fallback only) ----
__global__ __launch_bounds__(256) void gemm_nt_naive(
    const float* __restrict__ A, const float* __restrict__ B,
    const float* __restrict__ bias, float* __restrict__ C,
    int K, int ldc, int rows, int cols)
{
    int j = blockIdx.x * 16 + (threadIdx.x & 15);
    int i = blockIdx.y * 16 + (threadIdx.x >> 4);
    if (i >= rows || j >= cols) return;
    float acc = bias ? bias[j] : 0.0f;
    const float* Ar = A + (size_t)i * K;
    const float* Br = B + (size_t)j * K;
    for (int k = 0; k < K; ++k) acc = fmaf(Ar[k], Br[k], acc);
    C[(size_t)i * ldc + j] = acc;
}

// ---- f32 -> bf16 strip cast (fallback) ----
__global__ __launch_bounds__(256) void cast_bf16_n_kernel(
    const float* __restrict__ in, ushort_t* __restrict__ out, size_t n)
{
    size_t i = (size_t)blockIdx.x * 256 + threadIdx.x;
    for (; i < n; i += (size_t)gridDim.x * 256) {
        unsigned u = __float_as_uint(in[i]);
        out[i] = (ushort_t)((u + 0x7FFFu + ((u >> 16) & 1u)) >> 16);
    }
}

// ---- threshold-pruned top-k per row on bf16 scores (legacy, verified) ----
__device__ __forceinline__ unsigned mono16(unsigned b) {
    return (b & 0x8000u) ? (~b & 0xFFFFu) : (b | 0x8000u);
}
__device__ __forceinline__ float inv_mono16(unsigned m) {
    unsigned b = (m & 0x8000u) ? (m & 0x7FFFu) : (~m & 0xFFFFu);
    return __uint_as_float(b << 16);
}
__device__ __forceinline__ float scrub(float v) {
    unsigned u = __float_as_uint(v);
    if (((u >> 23) & 0xFFu) == 0xFFu) return -1.0e30f;
    if (v < -1.0e37f) return -1.0e30f;
    return v;
}

__global__ __launch_bounds__(256) void topk_kernel(
    const ushort_t* __restrict__ S, int N, int row_offset, int k_out,
    float* __restrict__ out_s, float* __restrict__ out_i)
{
    const int i = row_offset + blockIdx.x;
    const ushort_t* row = S + (size_t)blockIdx.x * N;
    const int t = threadIdx.x;
    const int lane = t & 63;
    const int w = t >> 6;
    const int nval = (i < N) ? i : N;
    const bool vec_ok = (N % 8) == 0;

    __shared__ unsigned hist4[4][257];
    __shared__ unsigned cand[CAND_CAP];
    __shared__ unsigned cand_cnt;
    __shared__ unsigned sT1, sAbove1, sT2;

    unsigned m16[32];
    unsigned tmax = 0;
#pragma unroll
    for (int c = 0; c < 4; ++c) {
        int jb = c * 2048 + t * 8;
        if (jb < nval) {
            ushort_t vv[8];
            if (vec_ok && jb + 8 <= N) {
                *(uint4*)vv = *(const uint4*)(row + jb);
            } else {
#pragma unroll
                for (int e = 0; e < 8; ++e) vv[e] = (jb + e < N) ? row[jb + e] : 0;
            }
#pragma unroll
            for (int e = 0; e < 8; ++e) {
                unsigned m = (jb + e < nval) ? mono16(vv[e]) : 0u;
                m16[c * 8 + e] = m;
                if (m > tmax) tmax = m;
            }
        } else {
#pragma unroll
            for (int e = 0; e < 8; ++e) m16[c * 8 + e] = 0u;
        }
    }

    if (t == 0) { sT1 = 0; sAbove1 = 0; sT2 = 0; cand_cnt = 0; }
#pragma unroll
    for (int q = 0; q < 4; ++q) hist4[q][t] = 0;
    __syncthreads();

    // Pass 1: histogram of thread-maxima top bytes (ONE atomic per thread)
    if (tmax) atomicAdd(&hist4[w][tmax >> 8], 1u);
    __syncthreads();
    if (w == 0) {
        int base = lane * 4;
        unsigned h[4];
#pragma unroll
        for (int r = 0; r < 4; ++r)
            h[r] = hist4[0][base + r] + hist4[1][base + r] +
                   hist4[2][base + r] + hist4[3][base + r];
        unsigned lsum = h[0] + h[1] + h[2] + h[3];
        unsigned suf = lsum;
#pragma unroll
        for (int off = 1; off < 64; off <<= 1) {
            unsigned o = __shfl_down(suf, off, 64);
            suf += (lane + off < 64) ? o : 0u;
        }
        unsigned Sr[5];
        Sr[4] = suf - lsum;
#pragma unroll
        for (int r = 3; r >= 0; --r) Sr[r] = Sr[r + 1] + h[r];
#pragma unroll
        for (int r = 0; r < 4; ++r)
            if (Sr[r] >= (unsigned)k_out && Sr[r + 1] < (unsigned)k_out) {
                sT1 = (unsigned)(base + r);
                sAbove1 = Sr[r + 1];
            }
    }
    __syncthreads();
    const unsigned T1 = sT1, above1 = sAbove1;

    // Pass 2: low byte of maxima within bin T1
#pragma unroll
    for (int q = 0; q < 4; ++q) hist4[q][t] = 0;
    __syncthreads();
    if (tmax && (tmax >> 8) == T1) atomicAdd(&hist4[w][tmax & 255u], 1u);
    __syncthreads();
    if (w == 0) {
        unsigned need = (unsigned)k_out - above1;
        int base = lane * 4;
        unsigned h[4];
#pragma unroll
        for (int r = 0; r < 4; ++r)
            h[r] = hist4[0][base + r] + hist4[1][base + r] +
                   hist4[2][base + r] + hist4[3][base + r];
        unsigned lsum = h[0] + h[1] + h[2] + h[3];
        unsigned suf = lsum;
#pragma unroll
        for (int off = 1; off < 64; off <<= 1) {
            unsigned o = __shfl_down(suf, off, 64);
            suf += (lane + off < 64) ? o : 0u;
        }
        unsigned Sr[5];
        Sr[4] = suf - lsum;
#pragma unroll
        for (int r = 3; r >= 0; --r) Sr[r] = Sr[r + 1] + h[r];
#pragma unroll
        for (int r = 0; r < 4; ++r)
            if (Sr[r] >= need && Sr[r + 1] < need)
                sT2 = (unsigned)(base + r);
    }
    __syncthreads();
    const unsigned Lt = (T1 << 8) | sT2;   // k-th largest thread-max (or 0)

    // Compact all row values >= Lt
#pragma unroll
    for (int s = 0; s < 32; ++s) {
        unsigned m = m16[s];
        if (m && m >= Lt) {
            unsigned idx = atomicAdd(&cand_cnt, 1u);
            if (idx < CAND_CAP) {
                int j = (s >> 3) * 2048 + t * 8 + (s & 7);
                cand[idx] = (m << 13) | (unsigned)(8191 - j);
            }
        }
    }
    __syncthreads();

    // Rank-by-counting extraction (keys unique -> ranks unique)
    const int m = (cand_cnt < CAND_CAP) ? (int)cand_cnt : CAND_CAP;
    const int reals = (k_out < nval) ? k_out : nval;
    for (int c = t; c < m; c += 256) {
        unsigned key = cand[c];
        int rank = 0;
        for (int x = 0; x < m; ++x) rank += (cand[x] > key) ? 1 : 0;
        if (rank < reals) {
            out_s[(size_t)i * k_out + rank] = scrub(inv_mono16(key >> 13));
            out_i[(size_t)i * k_out + rank] = (float)(8191 - (int)(key & 0x1FFFu));
        }
    }
    for (int r = reals + t; r < k_out; r += 256) {
        out_s[(size_t)i * k_out + r] = -1.0e30f;
        out_i[(size_t)i * k_out + r] = (float)r;
    }
}

extern "C" void kernel_launch(void* const* d_in, const int* in_sizes, int n_in,
                              void* d_out, int out_size, void* d_ws, size_t ws_size,
                              hipStream_t stream)
{
    const float* mentions = (const float*)d_in[0];   // [N x F]
    const float* W        = (const float*)d_in[1];   // [F x F]
    const float* bias     = (const float*)d_in[2];   // [F]

    const int F = in_sizes[2] > 0 ? in_sizes[2] : 1;
    const int N = in_sizes[0] / F;
    const int k_out = (N > 0) ? out_size / (2 * N) : 0;

    float* out_s = (float*)d_out;
    float* out_i = out_s + (size_t)N * k_out;

    prefill_kernel<<<256, 256, 0, stream>>>((float*)d_out, out_size);
    if (N <= 0 || k_out <= 0 || N > MAXN) return;

    dim3 blk(256);
    const bool tile_ok = (N % 128 == 0) && (F % 128 == 0);

    if (tile_ok) {
        // ws layout (bf16): Mb | Wb | Pb | sbuf
        ushort_t* Mb = (ushort_t*)d_ws;                    // N*F
        ushort_t* Wb = Mb + (size_t)N * F;                 // F*F
        ushort_t* Pb = Wb + (size_t)F * F;                 // N*F
        size_t fixed = ((size_t)2 * N * F + (size_t)F * F) * sizeof(ushort_t);
        size_t off = (fixed + 255) & ~(size_t)255;
        ushort_t* sbuf = (ushort_t*)((char*)d_ws + off);

        int chunk = (N < CHUNK_CAP) ? N : CHUNK_CAP;
        while (chunk > 128 && off + (size_t)chunk * N * sizeof(ushort_t) > ws_size)
            chunk >>= 1;

        if (off + (size_t)chunk * N * sizeof(ushort_t) <= ws_size) {
            cast_bf16_kernel<<<(N * F / 8 + 255) / 256, blk, 0, stream>>>(
                mentions, Mb, N * F);
            cast_bf16_kernel<<<(F * F / 8 + 255) / 256, blk, 0, stream>>>(
                W, Wb, F * F);

            // GEMM1: Pb = bf16(mentions @ W^T + b)   [N x F]
            // r23: 64x128-tile variant -> (F/128, N/64) = 1024 blocks = 4/CU
            gemm1_bf16_nt<<<dim3(F / 128, N / 64), blk, 0, stream>>>(
                Mb, Wb, bias, Pb, F, F);

            // GEMM2 (packed triangular grid, ONE dispatch) + top-k
            for (int r0 = 0; r0 < N; r0 += chunk) {
                int rows = (N - r0 < chunk) ? (N - r0) : chunk;
                int nby = rows / 128, base = r0 / 128;
                int T = nby * base + nby * (nby + 1) / 2;   // live tiles only
                gemm_bf16_nt<<<dim3(T, 1), blk, 0, stream>>>(
                    Pb + (size_t)r0 * F, Mb, nullptr, sbuf, F, N, base, 1);
                topk_kernel<<<rows, blk, 0, stream>>>(sbuf, N, r0, k_out, out_s, out_i);
            }
            return;
        }
    }

    // ---- fallback: naive f32 GEMMs + f32->bf16 cast of the score chunk ----
    {
        float* projf = (float*)d_ws;                           // N*F f32
        size_t o1 = (((size_t)N * F * sizeof(float)) + 255) & ~(size_t)255;
        float* sf = (float*)((char*)d_ws + o1);                // chunk*N f32
        int chunk = ((N + 127) / 128) * 128;
        while (chunk > 128 &&
               o1 + (size_t)chunk * N * (sizeof(float) + sizeof(ushort_t)) > ws_size)
            chunk >>= 1;
        size_t o2 = o1 + (((size_t)chunk * N * sizeof(float) + 255) & ~(size_t)255);
        ushort_t* sb = (ushort_t*)((char*)d_ws + o2);          // chunk*N bf16

        gemm_nt_naive<<<dim3((F + 15) / 16, (N + 15) / 16), blk, 0, stream>>>(
            mentions, W, bias, projf, F, F, N, F);
        for (int r0 = 0; r0 < N; r0 += chunk) {
            int rows = (N - r0 < chunk) ? (N - r0) : chunk;
            gemm_nt_naive<<<dim3((r0 + rows + 15) / 16, (rows + 15) / 16), blk, 0, stream>>>(
                projf + (size_t)r0 * F, mentions, nullptr, sf, F, N, rows, r0 + rows);
            cast_bf16_n_kernel<<<1024, blk, 0, stream>>>(sf, sb, (size_t)rows * N);
            topk_kernel<<<rows, blk, 0, stream>>>(sb, N, r0, k_out, out_s, out_i);
        }
    }
}

// Round 16
// 230.494 us; speedup vs baseline: 1.3178x; 1.0359x over previous
//
#include <hip/hip_runtime.h>

typedef unsigned short ushort_t;
typedef __attribute__((ext_vector_type(8))) short bf16x8;    // 8 bf16 = 4 VGPRs
typedef __attribute__((ext_vector_type(16))) float f32x16;   // 32x32 MFMA acc

#define MAXN 8192
#define CAND_CAP 2048
#define CHUNK_CAP 8192   // round-15: single GEMM2 dispatch beats 2 half-size ones

// round-24 journal:
//   MEASURED so far: GEMM2 96.5-98.5 (738 TF, structure ceiling), topk_legacy
//   36.5 (solid: r21-r19 differential), casts ~12 (roofline).
//   The remaining ~84us residual is INVARIANT across 4 GEMM1 variants
//   (r16 2/CU pipelined, r17 dbuf, r18/r19 128^2 4/CU, r23 64x128 1024-blk)
//   -> r23 falsified the occupancy theory. New hypothesis H2: GEMM1 is
//   really ~20-35 and the rest is fixed PER-DISPATCH overhead (6 kernels/
//   iter; r13/r14 history: +2 dispatches cost ~+58).
//   r24 experiment: cut dispatches 6 -> 4 with zero compute risk:
//     - revert GEMM1 to verified gemm_bf16_nt 2D (r23 variant <= neutral)
//     - fuse both casts into ONE float4-vectorized kernel
//     - drop prefill from main path (provably redundant: ranks 0..reals-1
//       all written by rank-by-count; fill loop covers reals..k_out-1)
//   Predict: H2 -> total ~210-222; H1 (GEMM1 real ~85) -> ~227-231.
//   If H1: next round launches GEMM1 TWICE as a direct duration probe.

// ---- zero-prefill d_out (fallback-path safety only) ----
__global__ void prefill_kernel(float* __restrict__ out, int n) {
    for (int i = blockIdx.x * 256 + threadIdx.x; i < n; i += gridDim.x * 256)
        out[i] = 0.0f;
}

// ---- r24: fused f32 -> bf16 cast of BOTH operands (RNE), float4 loads ----
// Grid-stride over (na + nb)/8 vector-slots; na, nb divisible by 8
// (guarded by tile_ok: N%128==0 && F%128==0).
__global__ __launch_bounds__(256) void cast2_bf16_kernel(
    const float* __restrict__ a, ushort_t* __restrict__ oa, unsigned na,
    const float* __restrict__ b, ushort_t* __restrict__ ob, unsigned nb)
{
    unsigned tot = (na + nb) >> 3;
    for (unsigned v = blockIdx.x * 256 + threadIdx.x; v < tot;
         v += gridDim.x * 256) {
        const float* src; ushort_t* dst; unsigned i8;
        unsigned e8 = v << 3;
        if (e8 < na) { src = a; dst = oa; i8 = e8; }
        else         { src = b; dst = ob; i8 = e8 - na; }
        float4 f0 = *(const float4*)(src + i8);
        float4 f1 = *(const float4*)(src + i8 + 4);
        float ff[8] = {f0.x, f0.y, f0.z, f0.w, f1.x, f1.y, f1.z, f1.w};
        ushort_t o[8];
#pragma unroll
        for (int q = 0; q < 8; ++q) {
            unsigned u = __float_as_uint(ff[q]);
            o[q] = (ushort_t)((u + 0x7FFFu + ((u >> 16) & 1u)) >> 16);
        }
        *(ushort4*)(dst + i8)     = make_ushort4(o[0], o[1], o[2], o[3]);
        *(ushort4*)(dst + i8 + 4) = make_ushort4(o[4], o[5], o[6], o[7]);
    }
}

// ---- f32 -> bf16 cast (RNE), 8/thread — kept for fallback path ----
__global__ __launch_bounds__(256) void cast_bf16_kernel(
    const float* __restrict__ in, ushort_t* __restrict__ out, int n)
{
    int i = (blockIdx.x * 256 + threadIdx.x) * 8;
    if (i >= n) return;
    ushort_t o[8];
#pragma unroll
    for (int q = 0; q < 8; ++q) {
        unsigned u = __float_as_uint(in[i + q]);
        o[q] = (ushort_t)((u + 0x7FFFu + ((u >> 16) & 1u)) >> 16);
    }
    *(ushort4*)(out + i)     = make_ushort4(o[0], o[1], o[2], o[3]);
    *(ushort4*)(out + i + 4) = make_ushort4(o[4], o[5], o[6], o[7]);
}

// async global->LDS, 16B per lane; lds dest = wave-uniform base + lane*16
__device__ __forceinline__ void gload_lds16(const ushort_t* g, void* lds) {
    __builtin_amdgcn_global_load_lds(
        (const __attribute__((address_space(1))) unsigned int*)g,
        (__attribute__((address_space(3))) unsigned int*)lds, 16, 0, 0);
}

// ---- bf16 MFMA NT GEMM: C[i][j] = bf16(sum_k A[i][k]*B[j][k] (+bias[j])) ----
// 128x128 block tile, BK=64, 4 waves 2x2; wave tile 64x64 = 2x2 of 32x32x16.
// __launch_bounds__(256,4) -> 4 blocks/CU.
// tri=1: PACKED triangular grid — blockIdx.x flat over live tiles only,
// with bijective XCD-chunk swizzle (m204) — r18: FETCH 224->181MB, keep.
// LDS 16B-slot swizzle: slot(m,kq) = m*8 + (kq ^ (m&7))  [conflict floor:
// residual 8.5M SQ_LDS_BANK_CONFLICT = inherent 2-way b128 aliasing, free].
__global__ __launch_bounds__(256, 4) void gemm_bf16_nt(
    const ushort_t* __restrict__ A, const ushort_t* __restrict__ B,
    const float* __restrict__ bias, ushort_t* __restrict__ C,
    int K, int ldc, int tbase, int tri)
{
    int bx, by;
    if (tri) {
        int f = blockIdx.x;
        {   // bijective XCD-chunk swizzle (ERRATA #11 / m204)
            int T  = (int)gridDim.x;
            int q  = T >> 3, r8 = T & 7;
            int xcd = f & 7, pos = f >> 3;
            f = (xcd < r8 ? xcd * (q + 1) : r8 * (q + 1) + (xcd - r8) * q) + pos;
        }
        int b = 0, off = 0;
        while (off + tbase + b + 1 <= f) { off += tbase + b + 1; ++b; }
        by = b; bx = f - off;
    } else {
        bx = blockIdx.x; by = blockIdx.y;
    }
    const int j0 = bx * 128;

    __shared__ __align__(16) ushort_t sA[128 * 64];
    __shared__ __align__(16) ushort_t sB[128 * 64];

    const int tid   = threadIdx.x;
    const int lane  = tid & 63;
    const int w     = tid >> 6;
    const int wr    = (w >> 1) * 64;
    const int wc    = (w & 1) * 64;
    const int l31   = lane & 31;
    const int khalf = lane >> 5;

    const ushort_t* Ab = A + (size_t)by * 128 * K;
    const ushort_t* Bb = B + (size_t)bx * 128 * K;

    f32x16 acc[2][2];
#pragma unroll
    for (int r = 0; r < 2; ++r)
#pragma unroll
        for (int c = 0; c < 2; ++c)
#pragma unroll
            for (int e = 0; e < 16; ++e) acc[r][c][e] = 0.0f;

    for (int k0 = 0; k0 < K; k0 += 64) {
#pragma unroll
        for (int qq = 0; qq < 4; ++qq) {
            int id = tid + qq * 256;           // 0..1023
            int m  = id >> 3;
            int kc = ((id & 7) ^ (m & 7)) * 8;
            unsigned lb = (unsigned)(((tid & ~63) + qq * 256) * 16);
            gload_lds16(Ab + (size_t)m * K + k0 + kc, (char*)sA + lb);
            gload_lds16(Bb + (size_t)m * K + k0 + kc, (char*)sB + lb);
        }
        __syncthreads();

#pragma unroll
        for (int h = 0; h < 4; ++h) {
            const int kq = h * 2 + khalf;
            bf16x8 fa[2], fb[2];
#pragma unroll
            for (int r = 0; r < 2; ++r) {
                int m = wr + r * 32 + l31;
                fa[r] = *(const bf16x8*)&sA[(m * 8 + (kq ^ (m & 7))) * 8];
            }
#pragma unroll
            for (int c = 0; c < 2; ++c) {
                int m = wc + c * 32 + l31;
                fb[c] = *(const bf16x8*)&sB[(m * 8 + (kq ^ (m & 7))) * 8];
            }
#pragma unroll
            for (int r = 0; r < 2; ++r)
#pragma unroll
                for (int c = 0; c < 2; ++c)
                    acc[r][c] = __builtin_amdgcn_mfma_f32_32x32x16_bf16(
                        fa[r], fb[c], acc[r][c], 0, 0, 0);
        }
        __syncthreads();
    }

    // Epilogue. 32x32 C/D layout (m74/m101): col = lane&31,
    // row = (reg&3) + 8*(reg>>2) + 4*(lane>>5). Store bf16 RNE.
#pragma unroll
    for (int r = 0; r < 2; ++r) {
#pragma unroll
        for (int c = 0; c < 2; ++c) {
            int colg = j0 + wc + c * 32 + l31;
            float bv = bias ? bias[colg] : 0.0f;
#pragma unroll
            for (int reg = 0; reg < 16; ++reg) {
                int rowl = (reg & 3) + 8 * (reg >> 2) + 4 * khalf;
                int row = by * 128 + wr + r * 32 + rowl;   // local row
                float v = acc[r][c][reg] + bv;
                unsigned u = __float_as_uint(v);
                C[(size_t)row * ldc + colg] =
                    (ushort_t)((u + 0x7FFFu + ((u >> 16) & 1u)) >> 16);
            }
        }
    }
}

// ---- fully-guarded naive fp32 NT GEMM -> f32 C (fallback only) ----
__global__ __launch_bounds__(256) void gemm_nt_naive(
    const float* __restrict__ A, const float* __restrict__ B,
    const float* __restrict__ bias, float* __restrict__ C,
    int K, int ldc, int rows, int cols)
{
    int j = blockIdx.x * 16 + (threadIdx.x & 15);
    int i = blockIdx.y * 16 + (threadIdx.x >> 4);
    if (i >= rows || j >= cols) return;
    float acc = bias ? bias[j] : 0.0f;
    const float* Ar = A + (size_t)i * K;
    const float* Br = B + (size_t)j * K;
    for (int k = 0; k < K; ++k) acc = fmaf(Ar[k], Br[k], acc);
    C[(size_t)i * ldc + j] = acc;
}

// ---- f32 -> bf16 strip cast (fallback) ----
__global__ __launch_bounds__(256) void cast_bf16_n_kernel(
    const float* __restrict__ in, ushort_t* __restrict__ out, size_t n)
{
    size_t i = (size_t)blockIdx.x * 256 + threadIdx.x;
    for (; i < n; i += (size_t)gridDim.x * 256) {
        unsigned u = __float_as_uint(in[i]);
        out[i] = (ushort_t)((u + 0x7FFFu + ((u >> 16) & 1u)) >> 16);
    }
}

// ---- threshold-pruned top-k per row on bf16 scores (legacy, verified) ----
__device__ __forceinline__ unsigned mono16(unsigned b) {
    return (b & 0x8000u) ? (~b & 0xFFFFu) : (b | 0x8000u);
}
__device__ __forceinline__ float inv_mono16(unsigned m) {
    unsigned b = (m & 0x8000u) ? (m & 0x7FFFu) : (~m & 0xFFFFu);
    return __uint_as_float(b << 16);
}
__device__ __forceinline__ float scrub(float v) {
    unsigned u = __float_as_uint(v);
    if (((u >> 23) & 0xFFu) == 0xFFu) return -1.0e30f;
    if (v < -1.0e37f) return -1.0e30f;
    return v;
}

__global__ __launch_bounds__(256) void topk_kernel(
    const ushort_t* __restrict__ S, int N, int row_offset, int k_out,
    float* __restrict__ out_s, float* __restrict__ out_i)
{
    const int i = row_offset + blockIdx.x;
    const ushort_t* row = S + (size_t)blockIdx.x * N;
    const int t = threadIdx.x;
    const int lane = t & 63;
    const int w = t >> 6;
    const int nval = (i < N) ? i : N;
    const bool vec_ok = (N % 8) == 0;

    __shared__ unsigned hist4[4][257];
    __shared__ unsigned cand[CAND_CAP];
    __shared__ unsigned cand_cnt;
    __shared__ unsigned sT1, sAbove1, sT2;

    unsigned m16[32];
    unsigned tmax = 0;
#pragma unroll
    for (int c = 0; c < 4; ++c) {
        int jb = c * 2048 + t * 8;
        if (jb < nval) {
            ushort_t vv[8];
            if (vec_ok && jb + 8 <= N) {
                *(uint4*)vv = *(const uint4*)(row + jb);
            } else {
#pragma unroll
                for (int e = 0; e < 8; ++e) vv[e] = (jb + e < N) ? row[jb + e] : 0;
            }
#pragma unroll
            for (int e = 0; e < 8; ++e) {
                unsigned m = (jb + e < nval) ? mono16(vv[e]) : 0u;
                m16[c * 8 + e] = m;
                if (m > tmax) tmax = m;
            }
        } else {
#pragma unroll
            for (int e = 0; e < 8; ++e) m16[c * 8 + e] = 0u;
        }
    }

    if (t == 0) { sT1 = 0; sAbove1 = 0; sT2 = 0; cand_cnt = 0; }
#pragma unroll
    for (int q = 0; q < 4; ++q) hist4[q][t] = 0;
    __syncthreads();

    // Pass 1: histogram of thread-maxima top bytes (ONE atomic per thread)
    if (tmax) atomicAdd(&hist4[w][tmax >> 8], 1u);
    __syncthreads();
    if (w == 0) {
        int base = lane * 4;
        unsigned h[4];
#pragma unroll
        for (int r = 0; r < 4; ++r)
            h[r] = hist4[0][base + r] + hist4[1][base + r] +
                   hist4[2][base + r] + hist4[3][base + r];
        unsigned lsum = h[0] + h[1] + h[2] + h[3];
        unsigned suf = lsum;
#pragma unroll
        for (int off = 1; off < 64; off <<= 1) {
            unsigned o = __shfl_down(suf, off, 64);
            suf += (lane + off < 64) ? o : 0u;
        }
        unsigned Sr[5];
        Sr[4] = suf - lsum;
#pragma unroll
        for (int r = 3; r >= 0; --r) Sr[r] = Sr[r + 1] + h[r];
#pragma unroll
        for (int r = 0; r < 4; ++r)
            if (Sr[r] >= (unsigned)k_out && Sr[r + 1] < (unsigned)k_out) {
                sT1 = (unsigned)(base + r);
                sAbove1 = Sr[r + 1];
            }
    }
    __syncthreads();
    const unsigned T1 = sT1, above1 = sAbove1;

    // Pass 2: low byte of maxima within bin T1
#pragma unroll
    for (int q = 0; q < 4; ++q) hist4[q][t] = 0;
    __syncthreads();
    if (tmax && (tmax >> 8) == T1) atomicAdd(&hist4[w][tmax & 255u], 1u);
    __syncthreads();
    if (w == 0) {
        unsigned need = (unsigned)k_out - above1;
        int base = lane * 4;
        unsigned h[4];
#pragma unroll
        for (int r = 0; r < 4; ++r)
            h[r] = hist4[0][base + r] + hist4[1][base + r] +
                   hist4[2][base + r] + hist4[3][base + r];
        unsigned lsum = h[0] + h[1] + h[2] + h[3];
        unsigned suf = lsum;
#pragma unroll
        for (int off = 1; off < 64; off <<= 1) {
            unsigned o = __shfl_down(suf, off, 64);
            suf += (lane + off < 64) ? o : 0u;
        }
        unsigned Sr[5];
        Sr[4] = suf - lsum;
#pragma unroll
        for (int r = 3; r >= 0; --r) Sr[r] = Sr[r + 1] + h[r];
#pragma unroll
        for (int r = 0; r < 4; ++r)
            if (Sr[r] >= need && Sr[r + 1] < need)
                sT2 = (unsigned)(base + r);
    }
    __syncthreads();
    const unsigned Lt = (T1 << 8) | sT2;   // k-th largest thread-max (or 0)

    // Compact all row values >= Lt
#pragma unroll
    for (int s = 0; s < 32; ++s) {
        unsigned m = m16[s];
        if (m && m >= Lt) {
            unsigned idx = atomicAdd(&cand_cnt, 1u);
            if (idx < CAND_CAP) {
                int j = (s >> 3) * 2048 + t * 8 + (s & 7);
                cand[idx] = (m << 13) | (unsigned)(8191 - j);
            }
        }
    }
    __syncthreads();

    // Rank-by-counting extraction (keys unique -> ranks unique).
    // Coverage: ranks of unique keys are exactly 0..m-1, so every output
    // slot [0, reals) is written; fill loop covers [reals, k_out).
    const int m = (cand_cnt < CAND_CAP) ? (int)cand_cnt : CAND_CAP;
    const int reals = (k_out < nval) ? k_out : nval;
    for (int c = t; c < m; c += 256) {
        unsigned key = cand[c];
        int rank = 0;
        for (int x = 0; x < m; ++x) rank += (cand[x] > key) ? 1 : 0;
        if (rank < reals) {
            out_s[(size_t)i * k_out + rank] = scrub(inv_mono16(key >> 13));
            out_i[(size_t)i * k_out + rank] = (float)(8191 - (int)(key & 0x1FFFu));
        }
    }
    for (int r = reals + t; r < k_out; r += 256) {
        out_s[(size_t)i * k_out + r] = -1.0e30f;
        out_i[(size_t)i * k_out + r] = (float)r;
    }
}

extern "C" void kernel_launch(void* const* d_in, const int* in_sizes, int n_in,
                              void* d_out, int out_size, void* d_ws, size_t ws_size,
                              hipStream_t stream)
{
    const float* mentions = (const float*)d_in[0];   // [N x F]
    const float* W        = (const float*)d_in[1];   // [F x F]
    const float* bias     = (const float*)d_in[2];   // [F]

    const int F = in_sizes[2] > 0 ? in_sizes[2] : 1;
    const int N = in_sizes[0] / F;
    const int k_out = (N > 0) ? out_size / (2 * N) : 0;

    float* out_s = (float*)d_out;
    float* out_i = out_s + (size_t)N * k_out;

    if (N <= 0 || k_out <= 0 || N > MAXN) {
        prefill_kernel<<<256, 256, 0, stream>>>((float*)d_out, out_size);
        return;
    }

    dim3 blk(256);
    const bool tile_ok = (N % 128 == 0) && (F % 128 == 0);

    if (tile_ok) {
        // ws layout (bf16): Mb | Wb | Pb | sbuf
        ushort_t* Mb = (ushort_t*)d_ws;                    // N*F
        ushort_t* Wb = Mb + (size_t)N * F;                 // F*F
        ushort_t* Pb = Wb + (size_t)F * F;                 // N*F
        size_t fixed = ((size_t)2 * N * F + (size_t)F * F) * sizeof(ushort_t);
        size_t off = (fixed + 255) & ~(size_t)255;
        ushort_t* sbuf = (ushort_t*)((char*)d_ws + off);

        int chunk = (N < CHUNK_CAP) ? N : CHUNK_CAP;
        while (chunk > 128 && off + (size_t)chunk * N * sizeof(ushort_t) > ws_size)
            chunk >>= 1;

        if (off + (size_t)chunk * N * sizeof(ushort_t) <= ws_size) {
            // r24: ONE fused cast dispatch (was prefill + 2 casts).
            // topk fully covers d_out in this path -> prefill dropped.
            cast2_bf16_kernel<<<2048, blk, 0, stream>>>(
                mentions, Mb, (unsigned)(N * F), W, Wb, (unsigned)(F * F));

            // GEMM1: Pb = bf16(mentions @ W^T + b)   [N x F]  (2D grid, tri=0)
            gemm_bf16_nt<<<dim3(F / 128, N / 128), blk, 0, stream>>>(
                Mb, Wb, bias, Pb, F, F, 0, 0);

            // GEMM2 (packed triangular grid, ONE dispatch) + top-k
            for (int r0 = 0; r0 < N; r0 += chunk) {
                int rows = (N - r0 < chunk) ? (N - r0) : chunk;
                int nby = rows / 128, base = r0 / 128;
                int T = nby * base + nby * (nby + 1) / 2;   // live tiles only
                gemm_bf16_nt<<<dim3(T, 1), blk, 0, stream>>>(
                    Pb + (size_t)r0 * F, Mb, nullptr, sbuf, F, N, base, 1);
                topk_kernel<<<rows, blk, 0, stream>>>(sbuf, N, r0, k_out, out_s, out_i);
            }
            return;
        }
    }

    // ---- fallback: naive f32 GEMMs + f32->bf16 cast of the score chunk ----
    {
        prefill_kernel<<<256, 256, 0, stream>>>((float*)d_out, out_size);
        float* projf = (float*)d_ws;                           // N*F f32
        size_t o1 = (((size_t)N * F * sizeof(float)) + 255) & ~(size_t)255;
        float* sf = (float*)((char*)d_ws + o1);                // chunk*N f32
        int chunk = ((N + 127) / 128) * 128;
        while (chunk > 128 &&
               o1 + (size_t)chunk * N * (sizeof(float) + sizeof(ushort_t)) > ws_size)
            chunk >>= 1;
        size_t o2 = o1 + (((size_t)chunk * N * sizeof(float) + 255) & ~(size_t)255);
        ushort_t* sb = (ushort_t*)((char*)d_ws + o2);          // chunk*N bf16

        gemm_nt_naive<<<dim3((F + 15) / 16, (N + 15) / 16), blk, 0, stream>>>(
            mentions, W, bias, projf, F, F, N, F);
        for (int r0 = 0; r0 < N; r0 += chunk) {
            int rows = (N - r0 < chunk) ? (N - r0) : chunk;
            gemm_nt_naive<<<dim3((r0 + rows + 15) / 16, (rows + 15) / 16), blk, 0, stream>>>(
                projf + (size_t)r0 * F, mentions, nullptr, sf, F, N, rows, r0 + rows);
            cast_bf16_n_kernel<<<1024, blk, 0, stream>>>(sf, sb, (size_t)rows * N);
            topk_kernel<<<rows, blk, 0, stream>>>(sb, N, r0, k_out, out_s, out_i);
        }
    }
}